// Round 1
// baseline (2599.901 us; speedup 1.0000x reference)
//
#include <hip/hip_runtime.h>
#include <math.h>

#define TS 12
#define HEADS 8
#define DH 8
#define DD 64
#define BB 16
#define NN 325
#define BN (BB*NN)               // 5200
#define TOT (TS*BN*DD)           // 3,993,600
#define ROWS_FC (BB*TS*NN)       // 62,400
constexpr float EPS_ = 1e-5f;
constexpr float SCALE_ = 0.35355339059327373f; // 1/sqrt(8)

// ---------------- K1: QKV GEMM + stats ----------------
__global__ __launch_bounds__(256) void qkv_gemm(
    const float* __restrict__ X, const float* __restrict__ STE,
    const float* __restrict__ Wqkv, const float* __restrict__ bqkv,
    float* __restrict__ Y, float* __restrict__ qsum, float* __restrict__ qsumsq)
{
    __shared__ float Wl[128*64];
    __shared__ float red[256];
    int t = blockIdx.y;
    int tid = threadIdx.x;
    for (int i = tid; i < 2048; i += 256)
        ((float4*)Wl)[i] = ((const float4*)Wqkv)[i];
    __syncthreads();
    int c = tid & 63, rl = tid >> 6;
    int r = blockIdx.x * 4 + rl;
    int b = r / NN, n = r % NN;
    const float* xr = X   + (((size_t)b*TS + t)*NN + n)*DD;
    const float* sr = STE + (((size_t)b*TS + t)*NN + n)*DD;
    float acc = bqkv[c];
    #pragma unroll 8
    for (int k = 0; k < 64; ++k) acc += xr[k] * Wl[k*64 + c];
    #pragma unroll 8
    for (int k = 0; k < 64; ++k) acc += sr[k] * Wl[(64+k)*64 + c];
    Y[((size_t)t*BN + r)*64 + c] = acc;
    // block-reduce stats (4 rows per block), then atomics
    red[tid] = acc; __syncthreads();
    if (tid < 64) atomicAdd(&qsum[t*64 + tid], red[tid] + red[tid+64] + red[tid+128] + red[tid+192]);
    __syncthreads();
    red[tid] = acc * acc; __syncthreads();
    if (tid < 64) atomicAdd(&qsumsq[t*64 + tid], red[tid] + red[tid+64] + red[tid+128] + red[tid+192]);
}

// ---------------- K2: finalize QKV BN stats ----------------
__global__ void qkv_stats(const float* __restrict__ qsum, const float* __restrict__ qsumsq,
                          const float* __restrict__ g, const float* __restrict__ be,
                          float* __restrict__ qsc, float* __restrict__ qsh)
{
    int i = blockIdx.x * blockDim.x + threadIdx.x;
    if (i >= TS*64) return;
    int c = i & 63;
    float mean = qsum[i] * (1.0f / BN);
    float var  = qsumsq[i] * (1.0f / BN) - mean*mean;
    float sc = g[c] * rsqrtf(var + EPS_);
    qsc[i] = sc;
    qsh[i] = be[c] - mean * sc;
}

// ---------------- K3: BN+ReLU + relayout to [t][b][h][n][d] ----------------
__global__ __launch_bounds__(256) void bn_relayout(
    const float* __restrict__ Y, const float* __restrict__ qsc, const float* __restrict__ qsh,
    float* __restrict__ qkv)
{
    size_t idx = (size_t)blockIdx.x * 256 + threadIdx.x;
    if (idx >= TOT) return;
    int c = (int)(idx & 63);
    size_t tr = idx >> 6;
    int t = (int)(tr / BN);
    int r = (int)(tr % BN);
    float v = fmaxf(Y[idx] * qsc[t*64 + c] + qsh[t*64 + c], 0.0f);
    int b = r / NN, n = r % NN, h = c >> 3, d = c & 7;
    qkv[((((size_t)t*BB + b)*HEADS + h)*NN + n)*DH + d] = v;
}

// ---------------- K4: attention for one step s, one (j,b,h) per block ----------------
__global__ __launch_bounds__(64) void attn_step(
    const float* __restrict__ qkv, float* __restrict__ ocat, int s)
{
    int j = blockIdx.x, b = blockIdx.y, h = blockIdx.z;
    __shared__ float4 kv[NN*2];  // 325 rows x 8 floats = 10.4 KB (K and V are the same tensor)
    const float4* ks = (const float4*)(qkv + (((size_t)j*BB + b)*HEADS + h)*(NN*DH));
    for (int i = threadIdx.x; i < NN*2; i += 64) kv[i] = ks[i];
    const float4* qs = (const float4*)(qkv + (((size_t)s*BB + b)*HEADS + h)*(NN*DH));

    float q[6][8], acc[6][8], den[6];
    #pragma unroll
    for (int rr = 0; rr < 6; ++rr) {
        int n = threadIdx.x + 64*rr;
        float4 q0 = make_float4(0.f,0.f,0.f,0.f), q1 = q0;
        if (n < NN) { q0 = qs[n*2]; q1 = qs[n*2+1]; }
        q[rr][0]=q0.x; q[rr][1]=q0.y; q[rr][2]=q0.z; q[rr][3]=q0.w;
        q[rr][4]=q1.x; q[rr][5]=q1.y; q[rr][6]=q1.z; q[rr][7]=q1.w;
        den[rr] = 0.f;
        #pragma unroll
        for (int d = 0; d < 8; ++d) acc[rr][d] = 0.f;
    }
    __syncthreads();

    for (int m = 0; m < NN; ++m) {
        float4 k0 = kv[m*2], k1 = kv[m*2+1];
        float kk[8] = {k0.x,k0.y,k0.z,k0.w,k1.x,k1.y,k1.z,k1.w};
        #pragma unroll
        for (int rr = 0; rr < 6; ++rr) {
            float sd = 0.f;
            #pragma unroll
            for (int d = 0; d < 8; ++d) sd += q[rr][d] * kk[d];
            // scores bounded (BN'd inputs): exp without max-subtraction is safe in f32
            float e = __expf(sd * SCALE_);
            den[rr] += e;
            #pragma unroll
            for (int d = 0; d < 8; ++d) acc[rr][d] += e * kk[d];
        }
    }

    #pragma unroll
    for (int rr = 0; rr < 6; ++rr) {
        int n = threadIdx.x + 64*rr;
        if (n < NN) {
            float inv = 1.0f / den[rr];
            float4 o0 = make_float4(acc[rr][0]*inv, acc[rr][1]*inv, acc[rr][2]*inv, acc[rr][3]*inv);
            float4 o1 = make_float4(acc[rr][4]*inv, acc[rr][5]*inv, acc[rr][6]*inv, acc[rr][7]*inv);
            float4* op = (float4*)(ocat + (size_t)(b*NN + n)*768 + j*64 + h*8);
            op[0] = o0; op[1] = o1;
        }
    }
}

// ---------------- K5: per-step linear, accumulate into Xo ----------------
__global__ __launch_bounds__(256) void lin_step(
    const float* __restrict__ ocat, const float* __restrict__ lin_w, const float* __restrict__ lin_b,
    float* __restrict__ Xo, int s)
{
    int tid = threadIdx.x;
    int c = tid & 63, rl = tid >> 6;
    int r = blockIdx.x * 4 + rl;
    int b = r / NN, n = r % NN;
    const float* orow = ocat + (size_t)r * 768;
    const float* w = lin_w + (size_t)s * 768 * 64;
    float acc = lin_b[s*64 + c];
    int KK = (s + 1) * 64;
    #pragma unroll 4
    for (int k = 0; k < KK; ++k) acc += orow[k] * w[k*64 + c];
    Xo[(((size_t)b*TS + s)*NN + n)*64 + c] = acc;
}

// ---------------- K6: fc GEMM (into d_out as scratch) + stats ----------------
__global__ __launch_bounds__(256) void fc_gemm(
    const float* __restrict__ Xo, const float* __restrict__ Wfc, const float* __restrict__ bfc,
    float* __restrict__ Yout, float* __restrict__ fsum, float* __restrict__ fsumsq)
{
    __shared__ float Wl[64*64];
    __shared__ float red[256];
    int tid = threadIdx.x;
    for (int i = tid; i < 1024; i += 256)
        ((float4*)Wl)[i] = ((const float4*)Wfc)[i];
    __syncthreads();
    int c = tid & 63, rl = tid >> 6;
    size_t r = (size_t)blockIdx.x * 4 + rl;
    const float* xr = Xo + r * 64;
    float acc = bfc[c];
    #pragma unroll 8
    for (int k = 0; k < 64; ++k) acc += xr[k] * Wl[k*64 + c];
    Yout[r*64 + c] = acc;
    red[tid] = acc; __syncthreads();
    if (tid < 64) atomicAdd(&fsum[tid], red[tid] + red[tid+64] + red[tid+128] + red[tid+192]);
    __syncthreads();
    red[tid] = acc * acc; __syncthreads();
    if (tid < 64) atomicAdd(&fsumsq[tid], red[tid] + red[tid+64] + red[tid+128] + red[tid+192]);
}

// ---------------- K7: finalize fc BN stats ----------------
__global__ void fc_stats(const float* __restrict__ fsum, const float* __restrict__ fsumsq,
                         const float* __restrict__ g, const float* __restrict__ be,
                         float* __restrict__ fsc, float* __restrict__ fsh)
{
    int c = threadIdx.x;
    if (c >= 64) return;
    float mean = fsum[c] * (1.0f / ROWS_FC);
    float var  = fsumsq[c] * (1.0f / ROWS_FC) - mean*mean;
    float sc = g[c] * rsqrtf(var + EPS_);
    fsc[c] = sc;
    fsh[c] = be[c] - mean * sc;
}

// ---------------- K8: final BN+ReLU in place on d_out ----------------
__global__ __launch_bounds__(256) void bn_out(
    float* __restrict__ out, const float* __restrict__ fsc, const float* __restrict__ fsh)
{
    size_t idx = (size_t)blockIdx.x * 256 + threadIdx.x;
    if (idx >= TOT) return;
    int c = (int)(idx & 63);
    out[idx] = fmaxf(out[idx] * fsc[c] + fsh[c], 0.0f);
}

extern "C" void kernel_launch(void* const* d_in, const int* in_sizes, int n_in,
                              void* d_out, int out_size, void* d_ws, size_t ws_size,
                              hipStream_t stream)
{
    const float* X     = (const float*)d_in[0];
    const float* STE   = (const float*)d_in[1];
    const float* Wqkv  = (const float*)d_in[2];
    const float* bqkv  = (const float*)d_in[3];
    const float* gqkv  = (const float*)d_in[4];
    const float* beqkv = (const float*)d_in[5];
    const float* lin_w = (const float*)d_in[6];
    const float* lin_b = (const float*)d_in[7];
    const float* Wfc   = (const float*)d_in[8];
    const float* bfc   = (const float*)d_in[9];
    const float* gfc   = (const float*)d_in[10];
    const float* befc  = (const float*)d_in[11];

    float* ws   = (float*)d_ws;
    float* Y    = ws;              // TOT floats; reused as ocat after relayout
    float* qkv  = ws + (size_t)TOT;
    float* Xo   = ws + (size_t)2*TOT;
    float* st   = ws + (size_t)3*TOT;
    float* qsum   = st;            // 768
    float* qsumsq = st + 768;      // 768
    float* fsum   = st + 1536;     // 64
    float* fsumsq = st + 1600;     // 64  -> first 1664 floats must be zeroed
    float* qsc    = st + 1664;     // 768
    float* qsh    = st + 2432;     // 768
    float* fsc    = st + 3200;     // 64
    float* fsh    = st + 3264;     // 64

    hipMemsetAsync(st, 0, 1664 * sizeof(float), stream);

    qkv_gemm<<<dim3(BN/4, TS), 256, 0, stream>>>(X, STE, Wqkv, bqkv, Y, qsum, qsumsq);
    qkv_stats<<<3, 256, 0, stream>>>(qsum, qsumsq, gqkv, beqkv, qsc, qsh);
    bn_relayout<<<TOT/256, 256, 0, stream>>>(Y, qsc, qsh, qkv);

    float* ocat = Y;  // Y no longer needed
    for (int s = 0; s < TS; ++s) {
        attn_step<<<dim3(s+1, BB, HEADS), 64, 0, stream>>>(qkv, ocat, s);
        lin_step<<<BN/4, 256, 0, stream>>>(ocat, lin_w, lin_b, Xo, s);
    }

    fc_gemm<<<ROWS_FC/4, 256, 0, stream>>>(Xo, Wfc, bfc, (float*)d_out, fsum, fsumsq);
    fc_stats<<<1, 64, 0, stream>>>(fsum, fsumsq, gfc, befc, fsc, fsh);
    bn_out<<<TOT/256, 256, 0, stream>>>((float*)d_out, fsc, fsh);
}

// Round 2
// 1109.043 us; speedup vs baseline: 2.3443x; 2.3443x over previous
//
#include <hip/hip_runtime.h>
#include <math.h>

#define TS 12
#define HEADS 8
#define DH 8
#define DD 64
#define BB 16
#define NN 325
#define BN (BB*NN)               // 5200
#define TOT (TS*BN*DD)           // 3,993,600
#define ROWS_FC (BB*TS*NN)       // 62,400
constexpr float EPS_ = 1e-5f;
constexpr float SCALE_ = 0.35355339059327373f; // 1/sqrt(8)

// ---------------- K1: QKV GEMM (16 rows/block, no stats) ----------------
__global__ __launch_bounds__(256) void qkv_gemm(
    const float* __restrict__ X, const float* __restrict__ STE,
    const float* __restrict__ Wqkv, const float* __restrict__ bqkv,
    float* __restrict__ Y)
{
    __shared__ float Wl[128*64];
    int t = blockIdx.y;
    int tid = threadIdx.x;
    for (int i = tid; i < 2048; i += 256)
        ((float4*)Wl)[i] = ((const float4*)Wqkv)[i];
    __syncthreads();
    int c = tid & 63, rl = tid >> 6;
    #pragma unroll
    for (int rr = 0; rr < 4; ++rr) {
        int r = blockIdx.x * 16 + rr * 4 + rl;
        int b = r / NN, n = r % NN;
        const float* xr = X   + (((size_t)b*TS + t)*NN + n)*DD;
        const float* sr = STE + (((size_t)b*TS + t)*NN + n)*DD;
        float acc = bqkv[c];
        #pragma unroll 8
        for (int k = 0; k < 64; ++k) acc += xr[k] * Wl[k*64 + c];
        #pragma unroll 8
        for (int k = 0; k < 64; ++k) acc += sr[k] * Wl[(64+k)*64 + c];
        Y[((size_t)t*BN + r)*64 + c] = acc;
    }
}

// ---------------- K2: column reduce (sum, sumsq) over [t][R][64] ----------------
// grid: (chunks, T); each chunk covers `chunkrows` rows. Low-contention atomics.
__global__ __launch_bounds__(256) void col_reduce(
    const float* __restrict__ src, float* __restrict__ osum, float* __restrict__ osumsq,
    int R, int chunkrows)
{
    __shared__ float red[256];
    int t = blockIdx.y;
    int tid = threadIdx.x;
    int c = tid & 63, rl = tid >> 6;
    int r0 = blockIdx.x * chunkrows;
    int r1 = r0 + chunkrows;
    float s = 0.f, s2 = 0.f;
    for (int r = r0 + rl; r < r1; r += 4) {
        float v = src[((size_t)t*R + r)*64 + c];
        s += v; s2 += v*v;
    }
    red[tid] = s; __syncthreads();
    if (tid < 64) atomicAdd(&osum[t*64 + tid], red[tid] + red[tid+64] + red[tid+128] + red[tid+192]);
    __syncthreads();
    red[tid] = s2; __syncthreads();
    if (tid < 64) atomicAdd(&osumsq[t*64 + tid], red[tid] + red[tid+64] + red[tid+128] + red[tid+192]);
}

// ---------------- K3: finalize QKV BN stats ----------------
__global__ void qkv_stats(const float* __restrict__ qsum, const float* __restrict__ qsumsq,
                          const float* __restrict__ g, const float* __restrict__ be,
                          float* __restrict__ qsc, float* __restrict__ qsh)
{
    int i = blockIdx.x * blockDim.x + threadIdx.x;
    if (i >= TS*64) return;
    int c = i & 63;
    float mean = qsum[i] * (1.0f / BN);
    float var  = qsumsq[i] * (1.0f / BN) - mean*mean;
    float sc = g[c] * rsqrtf(var + EPS_);
    qsc[i] = sc;
    qsh[i] = be[c] - mean * sc;
}

// ---------------- K4: BN+ReLU + relayout to [t][b][h][n][d] ----------------
__global__ __launch_bounds__(256) void bn_relayout(
    const float* __restrict__ Y, const float* __restrict__ qsc, const float* __restrict__ qsh,
    float* __restrict__ qkv)
{
    size_t idx = (size_t)blockIdx.x * 256 + threadIdx.x;
    if (idx >= TOT) return;
    int c = (int)(idx & 63);
    size_t tr = idx >> 6;
    int t = (int)(tr / BN);
    int r = (int)(tr % BN);
    float v = fmaxf(Y[idx] * qsc[t*64 + c] + qsh[t*64 + c], 0.0f);
    int b = r / NN, n = r % NN, h = c >> 3, d = c & 7;
    qkv[((((size_t)t*BB + b)*HEADS + h)*NN + n)*DH + d] = v;
}

// ---------------- K5: init Xo with lin_b ----------------
__global__ __launch_bounds__(256) void xo_init(
    float* __restrict__ Xo, const float* __restrict__ lin_b)
{
    size_t idx = (size_t)blockIdx.x * 256 + threadIdx.x;
    if (idx >= TOT) return;
    int c = (int)(idx & 63);
    size_t row = idx >> 6;
    int s = (int)((row / NN) % TS);
    Xo[idx] = lin_b[s*64 + c];
}

// ---------------- K6: fused attention + per-step linear ----------------
// One block (1 wave) per (pair p=(s,j), b, h). Computes softmax(Q_s K_j^T)V_j
// for all 325 q rows, then multiplies by lin_w[s][j*64+h*8 .. +8][:] and
// atomically accumulates into Xo[b][s][n][:] (coalesced 64-lane atomics).
__global__ __launch_bounds__(64) void attn_lin(
    const float* __restrict__ qkv, const float* __restrict__ lin_w,
    float* __restrict__ Xo)
{
    int p = blockIdx.x, b = blockIdx.y, h = blockIdx.z;
    int s = 0, base = 0;
    while (base + s + 1 <= p) { base += s + 1; ++s; }
    int j = p - base;

    __shared__ float4 kv[NN*2];   // K/V for (j,b,h): 10.4 KB; reused for o
    __shared__ float wl[512];     // lin_w slice (8 x 64)
    int tid = threadIdx.x;
    const float4* ks = (const float4*)(qkv + (((size_t)j*BB + b)*HEADS + h)*(NN*DH));
    for (int i = tid; i < NN*2; i += 64) kv[i] = ks[i];
    for (int i = tid; i < 512; i += 64) {
        int d = i >> 6, cc = i & 63;
        wl[i] = lin_w[(size_t)s*768*64 + (size_t)(j*64 + h*8 + d)*64 + cc];
    }
    const float4* qs = (const float4*)(qkv + (((size_t)s*BB + b)*HEADS + h)*(NN*DH));

    float q[6][8], acc[6][8], den[6];
    #pragma unroll
    for (int rr = 0; rr < 6; ++rr) {
        int n = tid + 64*rr;
        float4 q0 = make_float4(0.f,0.f,0.f,0.f), q1 = q0;
        if (n < NN) { q0 = qs[n*2]; q1 = qs[n*2+1]; }
        q[rr][0]=q0.x; q[rr][1]=q0.y; q[rr][2]=q0.z; q[rr][3]=q0.w;
        q[rr][4]=q1.x; q[rr][5]=q1.y; q[rr][6]=q1.z; q[rr][7]=q1.w;
        den[rr] = 0.f;
        #pragma unroll
        for (int d = 0; d < 8; ++d) acc[rr][d] = 0.f;
    }
    __syncthreads();

    for (int m = 0; m < NN; ++m) {
        float4 k0 = kv[m*2], k1 = kv[m*2+1];
        float kk[8] = {k0.x,k0.y,k0.z,k0.w,k1.x,k1.y,k1.z,k1.w};
        #pragma unroll
        for (int rr = 0; rr < 6; ++rr) {
            float sd = 0.f;
            #pragma unroll
            for (int d = 0; d < 8; ++d) sd += q[rr][d] * kk[d];
            // BN'd inputs -> bounded scores: exp without max-subtraction is safe in f32
            float e = __expf(sd * SCALE_);
            den[rr] += e;
            #pragma unroll
            for (int d = 0; d < 8; ++d) acc[rr][d] += e * kk[d];
        }
    }
    __syncthreads();

    // normalized o overwrites kv (no longer needed)
    #pragma unroll
    for (int rr = 0; rr < 6; ++rr) {
        int n = tid + 64*rr;
        if (n < NN) {
            float inv = 1.0f / den[rr];
            kv[n*2]   = make_float4(acc[rr][0]*inv, acc[rr][1]*inv, acc[rr][2]*inv, acc[rr][3]*inv);
            kv[n*2+1] = make_float4(acc[rr][4]*inv, acc[rr][5]*inv, acc[rr][6]*inv, acc[rr][7]*inv);
        }
    }
    __syncthreads();

    // linear slice: out[b,s,n,c] += sum_d o[n][d] * wl[d][c]
    float wc[8];
    #pragma unroll
    for (int d = 0; d < 8; ++d) wc[d] = wl[d*64 + tid];
    float* xbase = Xo + ((size_t)(b*TS + s)*NN)*64 + tid;
    for (int n = 0; n < NN; ++n) {
        const float* o8 = (const float*)&kv[n*2];   // broadcast LDS reads
        float v = o8[0]*wc[0] + o8[1]*wc[1] + o8[2]*wc[2] + o8[3]*wc[3]
                + o8[4]*wc[4] + o8[5]*wc[5] + o8[6]*wc[6] + o8[7]*wc[7];
        atomicAdd(xbase + (size_t)n*64, v);
    }
}

// ---------------- K7: fc GEMM (16 rows/block, no stats) ----------------
__global__ __launch_bounds__(256) void fc_gemm(
    const float* __restrict__ Xo, const float* __restrict__ Wfc, const float* __restrict__ bfc,
    float* __restrict__ Yout)
{
    __shared__ float Wl[64*64];
    int tid = threadIdx.x;
    for (int i = tid; i < 1024; i += 256)
        ((float4*)Wl)[i] = ((const float4*)Wfc)[i];
    __syncthreads();
    int c = tid & 63, rl = tid >> 6;
    #pragma unroll
    for (int rr = 0; rr < 4; ++rr) {
        size_t r = (size_t)blockIdx.x * 16 + rr * 4 + rl;
        const float* xr = Xo + r * 64;
        float acc = bfc[c];
        #pragma unroll 8
        for (int k = 0; k < 64; ++k) acc += xr[k] * Wl[k*64 + c];
        Yout[r*64 + c] = acc;
    }
}

// ---------------- K8: finalize fc BN stats ----------------
__global__ void fc_stats(const float* __restrict__ fsum, const float* __restrict__ fsumsq,
                         const float* __restrict__ g, const float* __restrict__ be,
                         float* __restrict__ fsc, float* __restrict__ fsh)
{
    int c = threadIdx.x;
    if (c >= 64) return;
    float mean = fsum[c] * (1.0f / ROWS_FC);
    float var  = fsumsq[c] * (1.0f / ROWS_FC) - mean*mean;
    float sc = g[c] * rsqrtf(var + EPS_);
    fsc[c] = sc;
    fsh[c] = be[c] - mean * sc;
}

// ---------------- K9: final BN+ReLU in place on d_out ----------------
__global__ __launch_bounds__(256) void bn_out(
    float* __restrict__ out, const float* __restrict__ fsc, const float* __restrict__ fsh)
{
    size_t idx = (size_t)blockIdx.x * 256 + threadIdx.x;
    if (idx >= TOT) return;
    int c = (int)(idx & 63);
    out[idx] = fmaxf(out[idx] * fsc[c] + fsh[c], 0.0f);
}

extern "C" void kernel_launch(void* const* d_in, const int* in_sizes, int n_in,
                              void* d_out, int out_size, void* d_ws, size_t ws_size,
                              hipStream_t stream)
{
    const float* X     = (const float*)d_in[0];
    const float* STE   = (const float*)d_in[1];
    const float* Wqkv  = (const float*)d_in[2];
    const float* bqkv  = (const float*)d_in[3];
    const float* gqkv  = (const float*)d_in[4];
    const float* beqkv = (const float*)d_in[5];
    const float* lin_w = (const float*)d_in[6];
    const float* lin_b = (const float*)d_in[7];
    const float* Wfc   = (const float*)d_in[8];
    const float* bfc   = (const float*)d_in[9];
    const float* gfc   = (const float*)d_in[10];
    const float* befc  = (const float*)d_in[11];

    float* ws   = (float*)d_ws;
    float* Y    = ws;                      // TOT floats
    float* qkv  = ws + (size_t)TOT;        // TOT floats
    float* Xo   = ws + (size_t)2*TOT;      // TOT floats
    float* st   = ws + (size_t)3*TOT;
    float* qsum   = st;            // 768
    float* qsumsq = st + 768;      // 768
    float* fsum   = st + 1536;     // 64
    float* fsumsq = st + 1600;     // 64  -> first 1664 floats zeroed each call
    float* qsc    = st + 1664;     // 768
    float* qsh    = st + 2432;     // 768
    float* fsc    = st + 3200;     // 64
    float* fsh    = st + 3264;     // 64

    hipMemsetAsync(st, 0, 1664 * sizeof(float), stream);

    qkv_gemm<<<dim3(BN/16, TS), 256, 0, stream>>>(X, STE, Wqkv, bqkv, Y);
    col_reduce<<<dim3(8, TS), 256, 0, stream>>>(Y, qsum, qsumsq, BN, BN/8);
    qkv_stats<<<3, 256, 0, stream>>>(qsum, qsumsq, gqkv, beqkv, qsc, qsh);
    bn_relayout<<<TOT/256, 256, 0, stream>>>(Y, qsc, qsh, qkv);
    xo_init<<<TOT/256, 256, 0, stream>>>(Xo, lin_b);

    attn_lin<<<dim3(78, BB, HEADS), 64, 0, stream>>>(qkv, lin_w, Xo);

    fc_gemm<<<ROWS_FC/16, 256, 0, stream>>>(Xo, Wfc, bfc, (float*)d_out);
    col_reduce<<<dim3(96, 1), 256, 0, stream>>>((float*)d_out, fsum, fsumsq, ROWS_FC, ROWS_FC/96);
    fc_stats<<<1, 64, 0, stream>>>(fsum, fsumsq, gfc, befc, fsc, fsh);
    bn_out<<<TOT/256, 256, 0, stream>>>((float*)d_out, fsc, fsh);
}

// Round 3
// 1071.394 us; speedup vs baseline: 2.4267x; 1.0351x over previous
//
#include <hip/hip_runtime.h>
#include <math.h>

#define TS 12
#define HEADS 8
#define DH 8
#define DD 64
#define BB 16
#define NN 325
#define BN (BB*NN)               // 5200
#define TOT (TS*BN*DD)           // 3,993,600
#define ROWS_FC (BB*TS*NN)       // 62,400
constexpr float EPS_ = 1e-5f;
constexpr float SCALE_ = 0.35355339059327373f; // 1/sqrt(8)

typedef float f32x2 __attribute__((ext_vector_type(2)));

// packed f32 FMA: d += a*b (2 lanes of f32 per instruction, CDNA dual-rate f32 path)
#define PK_FMA(d, a, b) asm("v_pk_fma_f32 %0, %1, %2, %0" : "+v"(d) : "v"(a), "v"(b))

// ---------------- K1: QKV GEMM (16 rows/block) ----------------
__global__ __launch_bounds__(256) void qkv_gemm(
    const float* __restrict__ X, const float* __restrict__ STE,
    const float* __restrict__ Wqkv, const float* __restrict__ bqkv,
    float* __restrict__ Y)
{
    __shared__ float Wl[128*64];
    int t = blockIdx.y;
    int tid = threadIdx.x;
    for (int i = tid; i < 2048; i += 256)
        ((float4*)Wl)[i] = ((const float4*)Wqkv)[i];
    __syncthreads();
    int c = tid & 63, rl = tid >> 6;
    #pragma unroll
    for (int rr = 0; rr < 4; ++rr) {
        int r = blockIdx.x * 16 + rr * 4 + rl;
        int b = r / NN, n = r % NN;
        const float* xr = X   + (((size_t)b*TS + t)*NN + n)*DD;
        const float* sr = STE + (((size_t)b*TS + t)*NN + n)*DD;
        float acc = bqkv[c];
        #pragma unroll 8
        for (int k = 0; k < 64; ++k) acc += xr[k] * Wl[k*64 + c];
        #pragma unroll 8
        for (int k = 0; k < 64; ++k) acc += sr[k] * Wl[(64+k)*64 + c];
        Y[((size_t)t*BN + r)*64 + c] = acc;
    }
}

// ---------------- K2: column reduce (sum, sumsq) over [t][R][64] ----------------
__global__ __launch_bounds__(256) void col_reduce(
    const float* __restrict__ src, float* __restrict__ osum, float* __restrict__ osumsq,
    int R, int chunkrows)
{
    __shared__ float red[256];
    int t = blockIdx.y;
    int tid = threadIdx.x;
    int c = tid & 63, rl = tid >> 6;
    int r0 = blockIdx.x * chunkrows;
    int r1 = r0 + chunkrows;
    float s = 0.f, s2 = 0.f;
    for (int r = r0 + rl; r < r1; r += 4) {
        float v = src[((size_t)t*R + r)*64 + c];
        s += v; s2 += v*v;
    }
    red[tid] = s; __syncthreads();
    if (tid < 64) atomicAdd(&osum[t*64 + tid], red[tid] + red[tid+64] + red[tid+128] + red[tid+192]);
    __syncthreads();
    red[tid] = s2; __syncthreads();
    if (tid < 64) atomicAdd(&osumsq[t*64 + tid], red[tid] + red[tid+64] + red[tid+128] + red[tid+192]);
}

// ---------------- K3: finalize QKV BN stats ----------------
__global__ void qkv_stats(const float* __restrict__ qsum, const float* __restrict__ qsumsq,
                          const float* __restrict__ g, const float* __restrict__ be,
                          float* __restrict__ qsc, float* __restrict__ qsh)
{
    int i = blockIdx.x * blockDim.x + threadIdx.x;
    if (i >= TS*64) return;
    int c = i & 63;
    float mean = qsum[i] * (1.0f / BN);
    float var  = qsumsq[i] * (1.0f / BN) - mean*mean;
    float sc = g[c] * rsqrtf(var + EPS_);
    qsc[i] = sc;
    qsh[i] = be[c] - mean * sc;
}

// ---------------- K4: BN+ReLU + relayout to [t][b][h][n][d] ----------------
__global__ __launch_bounds__(256) void bn_relayout(
    const float* __restrict__ Y, const float* __restrict__ qsc, const float* __restrict__ qsh,
    float* __restrict__ qkv)
{
    size_t idx = (size_t)blockIdx.x * 256 + threadIdx.x;
    if (idx >= TOT) return;
    int c = (int)(idx & 63);
    size_t tr = idx >> 6;
    int t = (int)(tr / BN);
    int r = (int)(tr % BN);
    float v = fmaxf(Y[idx] * qsc[t*64 + c] + qsh[t*64 + c], 0.0f);
    int b = r / NN, n = r % NN, h = c >> 3, d = c & 7;
    qkv[((((size_t)t*BB + b)*HEADS + h)*NN + n)*DH + d] = v;
}

// ---------------- K5: init Xo with lin_b ----------------
__global__ __launch_bounds__(256) void xo_init(
    float* __restrict__ Xo, const float* __restrict__ lin_b)
{
    size_t idx = (size_t)blockIdx.x * 256 + threadIdx.x;
    if (idx >= TOT) return;
    int c = (int)(idx & 63);
    size_t row = idx >> 6;
    int s = (int)((row / NN) % TS);
    Xo[idx] = lin_b[s*64 + c];
}

// ---------------- K6: fused attention + per-step linear ----------------
// One block (1 wave) per (pair p=(s,j), b, h). launch_bounds(64,1) so the
// compiler can hold q[6][8]+acc[6][8] in arch VGPRs (no AGPR shuttling).
// Inner loops use packed v_pk_fma_f32 (2 f32 FMA / instr).
__global__ __launch_bounds__(64, 1) void attn_lin(
    const float* __restrict__ qkv, const float* __restrict__ lin_w,
    float* __restrict__ Xo)
{
    int p = blockIdx.x, b = blockIdx.y, h = blockIdx.z;
    int s = 0, base = 0;
    while (base + s + 1 <= p) { base += s + 1; ++s; }
    int j = p - base;

    __shared__ float4 kv[NN*2];   // K/V for (j,b,h): 10.4 KB; reused for o
    __shared__ float wl[512];     // lin_w slice (8 x 64)
    int tid = threadIdx.x;
    const float4* ks = (const float4*)(qkv + (((size_t)j*BB + b)*HEADS + h)*(NN*DH));
    for (int i = tid; i < NN*2; i += 64) kv[i] = ks[i];
    for (int i = tid; i < 512; i += 64) {
        int d = i >> 6, cc = i & 63;
        wl[i] = lin_w[(size_t)s*768*64 + (size_t)(j*64 + h*8 + d)*64 + cc];
    }
    const float4* qs = (const float4*)(qkv + (((size_t)s*BB + b)*HEADS + h)*(NN*DH));

    f32x2 q2[6][4], acc2[6][4];
    float den[6];
    #pragma unroll
    for (int rr = 0; rr < 6; ++rr) {
        int n = tid + 64*rr;
        float4 a0 = make_float4(0.f,0.f,0.f,0.f), a1 = a0;
        if (n < NN) { a0 = qs[n*2]; a1 = qs[n*2+1]; }
        q2[rr][0] = f32x2{a0.x, a0.y}; q2[rr][1] = f32x2{a0.z, a0.w};
        q2[rr][2] = f32x2{a1.x, a1.y}; q2[rr][3] = f32x2{a1.z, a1.w};
        den[rr] = 0.f;
        #pragma unroll
        for (int i = 0; i < 4; ++i) acc2[rr][i] = f32x2{0.f, 0.f};
    }
    __syncthreads();

    for (int m = 0; m < NN; ++m) {
        float4 k0 = kv[m*2], k1 = kv[m*2+1];
        f32x2 kk2[4] = { f32x2{k0.x,k0.y}, f32x2{k0.z,k0.w},
                         f32x2{k1.x,k1.y}, f32x2{k1.z,k1.w} };
        #pragma unroll
        for (int rr = 0; rr < 6; ++rr) {
            f32x2 d2 = f32x2{0.f, 0.f};
            #pragma unroll
            for (int i = 0; i < 4; ++i) PK_FMA(d2, q2[rr][i], kk2[i]);
            float sd = (d2.x + d2.y) * SCALE_;
            // BN'd inputs -> bounded scores: exp without max-subtraction safe in f32
            float e = __expf(sd);
            den[rr] += e;
            f32x2 e2 = f32x2{e, e};
            #pragma unroll
            for (int i = 0; i < 4; ++i) PK_FMA(acc2[rr][i], e2, kk2[i]);
        }
    }
    __syncthreads();

    // normalized o overwrites kv (no longer needed)
    #pragma unroll
    for (int rr = 0; rr < 6; ++rr) {
        int n = tid + 64*rr;
        if (n < NN) {
            float inv = 1.0f / den[rr];
            kv[n*2]   = make_float4(acc2[rr][0].x*inv, acc2[rr][0].y*inv,
                                    acc2[rr][1].x*inv, acc2[rr][1].y*inv);
            kv[n*2+1] = make_float4(acc2[rr][2].x*inv, acc2[rr][2].y*inv,
                                    acc2[rr][3].x*inv, acc2[rr][3].y*inv);
        }
    }
    __syncthreads();

    // linear slice: Xo[b,s,n,c] += sum_d o[n][d] * wl[d][c]
    f32x2 wc2[4];
    #pragma unroll
    for (int i = 0; i < 4; ++i)
        wc2[i] = f32x2{ wl[(2*i)*64 + tid], wl[(2*i+1)*64 + tid] };
    float* xbase = Xo + ((size_t)(b*TS + s)*NN)*64 + tid;
    for (int n = 0; n < NN; ++n) {
        float4 oa = kv[n*2], ob = kv[n*2+1];   // wave-uniform broadcast reads
        f32x2 o2[4] = { f32x2{oa.x,oa.y}, f32x2{oa.z,oa.w},
                        f32x2{ob.x,ob.y}, f32x2{ob.z,ob.w} };
        f32x2 v2 = f32x2{0.f, 0.f};
        #pragma unroll
        for (int i = 0; i < 4; ++i) PK_FMA(v2, o2[i], wc2[i]);
        atomicAdd(xbase + (size_t)n*64, v2.x + v2.y);
    }
}

// ---------------- K7: fc GEMM (16 rows/block) ----------------
__global__ __launch_bounds__(256) void fc_gemm(
    const float* __restrict__ Xo, const float* __restrict__ Wfc, const float* __restrict__ bfc,
    float* __restrict__ Yout)
{
    __shared__ float Wl[64*64];
    int tid = threadIdx.x;
    for (int i = tid; i < 1024; i += 256)
        ((float4*)Wl)[i] = ((const float4*)Wfc)[i];
    __syncthreads();
    int c = tid & 63, rl = tid >> 6;
    #pragma unroll
    for (int rr = 0; rr < 4; ++rr) {
        size_t r = (size_t)blockIdx.x * 16 + rr * 4 + rl;
        const float* xr = Xo + r * 64;
        float acc = bfc[c];
        #pragma unroll 8
        for (int k = 0; k < 64; ++k) acc += xr[k] * Wl[k*64 + c];
        Yout[r*64 + c] = acc;
    }
}

// ---------------- K8: finalize fc BN stats ----------------
__global__ void fc_stats(const float* __restrict__ fsum, const float* __restrict__ fsumsq,
                         const float* __restrict__ g, const float* __restrict__ be,
                         float* __restrict__ fsc, float* __restrict__ fsh)
{
    int c = threadIdx.x;
    if (c >= 64) return;
    float mean = fsum[c] * (1.0f / ROWS_FC);
    float var  = fsumsq[c] * (1.0f / ROWS_FC) - mean*mean;
    float sc = g[c] * rsqrtf(var + EPS_);
    fsc[c] = sc;
    fsh[c] = be[c] - mean * sc;
}

// ---------------- K9: final BN+ReLU in place on d_out ----------------
__global__ __launch_bounds__(256) void bn_out(
    float* __restrict__ out, const float* __restrict__ fsc, const float* __restrict__ fsh)
{
    size_t idx = (size_t)blockIdx.x * 256 + threadIdx.x;
    if (idx >= TOT) return;
    int c = (int)(idx & 63);
    out[idx] = fmaxf(out[idx] * fsc[c] + fsh[c], 0.0f);
}

extern "C" void kernel_launch(void* const* d_in, const int* in_sizes, int n_in,
                              void* d_out, int out_size, void* d_ws, size_t ws_size,
                              hipStream_t stream)
{
    const float* X     = (const float*)d_in[0];
    const float* STE   = (const float*)d_in[1];
    const float* Wqkv  = (const float*)d_in[2];
    const float* bqkv  = (const float*)d_in[3];
    const float* gqkv  = (const float*)d_in[4];
    const float* beqkv = (const float*)d_in[5];
    const float* lin_w = (const float*)d_in[6];
    const float* lin_b = (const float*)d_in[7];
    const float* Wfc   = (const float*)d_in[8];
    const float* bfc   = (const float*)d_in[9];
    const float* gfc   = (const float*)d_in[10];
    const float* befc  = (const float*)d_in[11];

    float* ws   = (float*)d_ws;
    float* Y    = ws;                      // TOT floats
    float* qkv  = ws + (size_t)TOT;        // TOT floats
    float* Xo   = ws + (size_t)2*TOT;      // TOT floats
    float* st   = ws + (size_t)3*TOT;
    float* qsum   = st;            // 768
    float* qsumsq = st + 768;      // 768
    float* fsum   = st + 1536;     // 64
    float* fsumsq = st + 1600;     // 64  -> first 1664 floats zeroed each call
    float* qsc    = st + 1664;     // 768
    float* qsh    = st + 2432;     // 768
    float* fsc    = st + 3200;     // 64
    float* fsh    = st + 3264;     // 64

    hipMemsetAsync(st, 0, 1664 * sizeof(float), stream);

    qkv_gemm<<<dim3(BN/16, TS), 256, 0, stream>>>(X, STE, Wqkv, bqkv, Y);
    col_reduce<<<dim3(8, TS), 256, 0, stream>>>(Y, qsum, qsumsq, BN, BN/8);
    qkv_stats<<<3, 256, 0, stream>>>(qsum, qsumsq, gqkv, beqkv, qsc, qsh);
    bn_relayout<<<TOT/256, 256, 0, stream>>>(Y, qsc, qsh, qkv);
    xo_init<<<TOT/256, 256, 0, stream>>>(Xo, lin_b);

    attn_lin<<<dim3(78, BB, HEADS), 64, 0, stream>>>(qkv, lin_w, Xo);

    fc_gemm<<<ROWS_FC/16, 256, 0, stream>>>(Xo, Wfc, bfc, (float*)d_out);
    col_reduce<<<dim3(96, 1), 256, 0, stream>>>((float*)d_out, fsum, fsumsq, ROWS_FC, ROWS_FC/96);
    fc_stats<<<1, 64, 0, stream>>>(fsum, fsumsq, gfc, befc, fsc, fsh);
    bn_out<<<TOT/256, 256, 0, stream>>>((float*)d_out, fsc, fsh);
}

// Round 4
// 1036.333 us; speedup vs baseline: 2.5088x; 1.0338x over previous
//
#include <hip/hip_runtime.h>
#include <math.h>

#define TS 12
#define HEADS 8
#define DH 8
#define DD 64
#define BB 16
#define NN 325
#define BN (BB*NN)               // 5200
#define TOT (TS*BN*DD)           // 3,993,600
#define ROWS_FC (BB*TS*NN)       // 62,400
constexpr float EPS_ = 1e-5f;
constexpr float SCALE_ = 0.35355339059327373f; // 1/sqrt(8)

typedef float f32x2 __attribute__((ext_vector_type(2)));

// packed f32 FMA: d += a*b (2 f32 FMA per instruction)
#define PK_FMA(d, a, b) asm("v_pk_fma_f32 %0, %1, %2, %0" : "+v"(d) : "v"(a), "v"(b))

#define AT_T 128   // threads per attn block (2 waves)
#define AT_R 3     // q rows per lane (128*3 = 384 >= 325)

// ---------------- K1: QKV GEMM (16 rows/block) ----------------
__global__ __launch_bounds__(256) void qkv_gemm(
    const float* __restrict__ X, const float* __restrict__ STE,
    const float* __restrict__ Wqkv, const float* __restrict__ bqkv,
    float* __restrict__ Y)
{
    __shared__ float Wl[128*64];
    int t = blockIdx.y;
    int tid = threadIdx.x;
    for (int i = tid; i < 2048; i += 256)
        ((float4*)Wl)[i] = ((const float4*)Wqkv)[i];
    __syncthreads();
    int c = tid & 63, rl = tid >> 6;
    #pragma unroll
    for (int rr = 0; rr < 4; ++rr) {
        int r = blockIdx.x * 16 + rr * 4 + rl;
        int b = r / NN, n = r % NN;
        const float* xr = X   + (((size_t)b*TS + t)*NN + n)*DD;
        const float* sr = STE + (((size_t)b*TS + t)*NN + n)*DD;
        float acc = bqkv[c];
        #pragma unroll 8
        for (int k = 0; k < 64; ++k) acc += xr[k] * Wl[k*64 + c];
        #pragma unroll 8
        for (int k = 0; k < 64; ++k) acc += sr[k] * Wl[(64+k)*64 + c];
        Y[((size_t)t*BN + r)*64 + c] = acc;
    }
}

// ---------------- K2: column reduce (sum, sumsq) over [t][R][64] ----------------
__global__ __launch_bounds__(256) void col_reduce(
    const float* __restrict__ src, float* __restrict__ osum, float* __restrict__ osumsq,
    int R, int chunkrows)
{
    __shared__ float red[256];
    int t = blockIdx.y;
    int tid = threadIdx.x;
    int c = tid & 63, rl = tid >> 6;
    int r0 = blockIdx.x * chunkrows;
    int r1 = r0 + chunkrows;
    float s = 0.f, s2 = 0.f;
    for (int r = r0 + rl; r < r1; r += 4) {
        float v = src[((size_t)t*R + r)*64 + c];
        s += v; s2 += v*v;
    }
    red[tid] = s; __syncthreads();
    if (tid < 64) atomicAdd(&osum[t*64 + tid], red[tid] + red[tid+64] + red[tid+128] + red[tid+192]);
    __syncthreads();
    red[tid] = s2; __syncthreads();
    if (tid < 64) atomicAdd(&osumsq[t*64 + tid], red[tid] + red[tid+64] + red[tid+128] + red[tid+192]);
}

// ---------------- K3: finalize QKV BN stats ----------------
__global__ void qkv_stats(const float* __restrict__ qsum, const float* __restrict__ qsumsq,
                          const float* __restrict__ g, const float* __restrict__ be,
                          float* __restrict__ qsc, float* __restrict__ qsh)
{
    int i = blockIdx.x * blockDim.x + threadIdx.x;
    if (i >= TS*64) return;
    int c = i & 63;
    float mean = qsum[i] * (1.0f / BN);
    float var  = qsumsq[i] * (1.0f / BN) - mean*mean;
    float sc = g[c] * rsqrtf(var + EPS_);
    qsc[i] = sc;
    qsh[i] = be[c] - mean * sc;
}

// ---------------- K4: BN+ReLU + relayout to [t][b][h][n][d] ----------------
__global__ __launch_bounds__(256) void bn_relayout(
    const float* __restrict__ Y, const float* __restrict__ qsc, const float* __restrict__ qsh,
    float* __restrict__ qkv)
{
    size_t idx = (size_t)blockIdx.x * 256 + threadIdx.x;
    if (idx >= TOT) return;
    int c = (int)(idx & 63);
    size_t tr = idx >> 6;
    int t = (int)(tr / BN);
    int r = (int)(tr % BN);
    float v = fmaxf(Y[idx] * qsc[t*64 + c] + qsh[t*64 + c], 0.0f);
    int b = r / NN, n = r % NN, h = c >> 3, d = c & 7;
    qkv[((((size_t)t*BB + b)*HEADS + h)*NN + n)*DH + d] = v;
}

// ---------------- K5: init Xo with lin_b ----------------
__global__ __launch_bounds__(256) void xo_init(
    float* __restrict__ Xo, const float* __restrict__ lin_b)
{
    size_t idx = (size_t)blockIdx.x * 256 + threadIdx.x;
    if (idx >= TOT) return;
    int c = (int)(idx & 63);
    size_t row = idx >> 6;
    int s = (int)((row / NN) % TS);
    Xo[idx] = lin_b[s*64 + c];
}

// ---------------- K6: fused attention + per-step linear ----------------
// One block (2 waves) per (pair p=(s,j), b, h). R=3 q-rows per lane so the
// whole live set (q 24 + acc 24 + misc) fits in <=128 arch VGPRs -> no AGPR
// shuttling around the packed-FMA inline asm. launch_bounds(128,4) = 4
// waves/SIMD target.
__global__ __launch_bounds__(AT_T, 4) void attn_lin(
    const float* __restrict__ qkv, const float* __restrict__ lin_w,
    float* __restrict__ Xo)
{
    int p = blockIdx.x, b = blockIdx.y, h = blockIdx.z;
    int s = 0, base = 0;
    while (base + s + 1 <= p) { base += s + 1; ++s; }
    int j = p - base;

    __shared__ float4 kv[NN*2];   // K/V for (j,b,h): 10.4 KB; reused for o
    __shared__ float wl[512];     // lin_w slice (8 x 64)
    int tid = threadIdx.x;
    const float4* ks = (const float4*)(qkv + (((size_t)j*BB + b)*HEADS + h)*(NN*DH));
    for (int i = tid; i < NN*2; i += AT_T) kv[i] = ks[i];
    for (int i = tid; i < 512; i += AT_T) {
        int d = i >> 6, cc = i & 63;
        wl[i] = lin_w[(size_t)s*768*64 + (size_t)(j*64 + h*8 + d)*64 + cc];
    }
    const float4* qs = (const float4*)(qkv + (((size_t)s*BB + b)*HEADS + h)*(NN*DH));

    f32x2 q2[AT_R][4], acc2[AT_R][4];
    float den[AT_R];
    #pragma unroll
    for (int rr = 0; rr < AT_R; ++rr) {
        int n = tid + AT_T*rr;
        float4 a0 = make_float4(0.f,0.f,0.f,0.f), a1 = a0;
        if (n < NN) { a0 = qs[n*2]; a1 = qs[n*2+1]; }
        // pre-scale Q by 1/sqrt(d): kills the per-score multiply
        q2[rr][0] = f32x2{a0.x*SCALE_, a0.y*SCALE_};
        q2[rr][1] = f32x2{a0.z*SCALE_, a0.w*SCALE_};
        q2[rr][2] = f32x2{a1.x*SCALE_, a1.y*SCALE_};
        q2[rr][3] = f32x2{a1.z*SCALE_, a1.w*SCALE_};
        den[rr] = 0.f;
        #pragma unroll
        for (int i = 0; i < 4; ++i) acc2[rr][i] = f32x2{0.f, 0.f};
    }
    __syncthreads();

    #pragma unroll 2
    for (int m = 0; m < NN; ++m) {
        float4 k0 = kv[m*2], k1 = kv[m*2+1];
        f32x2 kk2[4] = { f32x2{k0.x,k0.y}, f32x2{k0.z,k0.w},
                         f32x2{k1.x,k1.y}, f32x2{k1.z,k1.w} };
        #pragma unroll
        for (int rr = 0; rr < AT_R; ++rr) {
            f32x2 d2 = f32x2{0.f, 0.f};
            #pragma unroll
            for (int i = 0; i < 4; ++i) PK_FMA(d2, q2[rr][i], kk2[i]);
            // BN'd inputs -> bounded scores: exp without max-subtraction safe in f32
            float e = __expf(d2.x + d2.y);
            den[rr] += e;
            f32x2 e2 = f32x2{e, e};
            #pragma unroll
            for (int i = 0; i < 4; ++i) PK_FMA(acc2[rr][i], e2, kk2[i]);
        }
    }
    __syncthreads();

    // normalized o overwrites kv (no longer needed)
    #pragma unroll
    for (int rr = 0; rr < AT_R; ++rr) {
        int n = tid + AT_T*rr;
        if (n < NN) {
            float inv = 1.0f / den[rr];
            kv[n*2]   = make_float4(acc2[rr][0].x*inv, acc2[rr][0].y*inv,
                                    acc2[rr][1].x*inv, acc2[rr][1].y*inv);
            kv[n*2+1] = make_float4(acc2[rr][2].x*inv, acc2[rr][2].y*inv,
                                    acc2[rr][3].x*inv, acc2[rr][3].y*inv);
        }
    }
    __syncthreads();

    // linear slice: Xo[b,s,n,c] += sum_d o[n][d] * wl[d][c]; waves split n range
    int c = tid & 63;
    int wv = tid >> 6;                 // 0 or 1
    f32x2 wc2[4];
    #pragma unroll
    for (int i = 0; i < 4; ++i)
        wc2[i] = f32x2{ wl[(2*i)*64 + c], wl[(2*i+1)*64 + c] };
    int n0 = wv * 163;
    int n1 = (wv == 0) ? 163 : NN;
    float* xbase = Xo + ((size_t)(b*TS + s)*NN)*64 + c;
    for (int n = n0; n < n1; ++n) {
        float4 oa = kv[n*2], ob = kv[n*2+1];   // wave-uniform broadcast reads
        f32x2 o2[4] = { f32x2{oa.x,oa.y}, f32x2{oa.z,oa.w},
                        f32x2{ob.x,ob.y}, f32x2{ob.z,ob.w} };
        f32x2 v2 = f32x2{0.f, 0.f};
        #pragma unroll
        for (int i = 0; i < 4; ++i) PK_FMA(v2, o2[i], wc2[i]);
        atomicAdd(xbase + (size_t)n*64, v2.x + v2.y);
    }
}

// ---------------- K7: fc GEMM (16 rows/block) ----------------
__global__ __launch_bounds__(256) void fc_gemm(
    const float* __restrict__ Xo, const float* __restrict__ Wfc, const float* __restrict__ bfc,
    float* __restrict__ Yout)
{
    __shared__ float Wl[64*64];
    int tid = threadIdx.x;
    for (int i = tid; i < 1024; i += 256)
        ((float4*)Wl)[i] = ((const float4*)Wfc)[i];
    __syncthreads();
    int c = tid & 63, rl = tid >> 6;
    #pragma unroll
    for (int rr = 0; rr < 4; ++rr) {
        size_t r = (size_t)blockIdx.x * 16 + rr * 4 + rl;
        const float* xr = Xo + r * 64;
        float acc = bfc[c];
        #pragma unroll 8
        for (int k = 0; k < 64; ++k) acc += xr[k] * Wl[k*64 + c];
        Yout[r*64 + c] = acc;
    }
}

// ---------------- K8: finalize fc BN stats ----------------
__global__ void fc_stats(const float* __restrict__ fsum, const float* __restrict__ fsumsq,
                         const float* __restrict__ g, const float* __restrict__ be,
                         float* __restrict__ fsc, float* __restrict__ fsh)
{
    int c = threadIdx.x;
    if (c >= 64) return;
    float mean = fsum[c] * (1.0f / ROWS_FC);
    float var  = fsumsq[c] * (1.0f / ROWS_FC) - mean*mean;
    float sc = g[c] * rsqrtf(var + EPS_);
    fsc[c] = sc;
    fsh[c] = be[c] - mean * sc;
}

// ---------------- K9: final BN+ReLU in place on d_out ----------------
__global__ __launch_bounds__(256) void bn_out(
    float* __restrict__ out, const float* __restrict__ fsc, const float* __restrict__ fsh)
{
    size_t idx = (size_t)blockIdx.x * 256 + threadIdx.x;
    if (idx >= TOT) return;
    int c = (int)(idx & 63);
    out[idx] = fmaxf(out[idx] * fsc[c] + fsh[c], 0.0f);
}

extern "C" void kernel_launch(void* const* d_in, const int* in_sizes, int n_in,
                              void* d_out, int out_size, void* d_ws, size_t ws_size,
                              hipStream_t stream)
{
    const float* X     = (const float*)d_in[0];
    const float* STE   = (const float*)d_in[1];
    const float* Wqkv  = (const float*)d_in[2];
    const float* bqkv  = (const float*)d_in[3];
    const float* gqkv  = (const float*)d_in[4];
    const float* beqkv = (const float*)d_in[5];
    const float* lin_w = (const float*)d_in[6];
    const float* lin_b = (const float*)d_in[7];
    const float* Wfc   = (const float*)d_in[8];
    const float* bfc   = (const float*)d_in[9];
    const float* gfc   = (const float*)d_in[10];
    const float* befc  = (const float*)d_in[11];

    float* ws   = (float*)d_ws;
    float* Y    = ws;                      // TOT floats
    float* qkv  = ws + (size_t)TOT;        // TOT floats
    float* Xo   = ws + (size_t)2*TOT;      // TOT floats
    float* st   = ws + (size_t)3*TOT;
    float* qsum   = st;            // 768
    float* qsumsq = st + 768;      // 768
    float* fsum   = st + 1536;     // 64
    float* fsumsq = st + 1600;     // 64  -> first 1664 floats zeroed each call
    float* qsc    = st + 1664;     // 768
    float* qsh    = st + 2432;     // 768
    float* fsc    = st + 3200;     // 64
    float* fsh    = st + 3264;     // 64

    hipMemsetAsync(st, 0, 1664 * sizeof(float), stream);

    qkv_gemm<<<dim3(BN/16, TS), 256, 0, stream>>>(X, STE, Wqkv, bqkv, Y);
    col_reduce<<<dim3(8, TS), 256, 0, stream>>>(Y, qsum, qsumsq, BN, BN/8);
    qkv_stats<<<3, 256, 0, stream>>>(qsum, qsumsq, gqkv, beqkv, qsc, qsh);
    bn_relayout<<<TOT/256, 256, 0, stream>>>(Y, qsc, qsh, qkv);
    xo_init<<<TOT/256, 256, 0, stream>>>(Xo, lin_b);

    attn_lin<<<dim3(78, BB, HEADS), AT_T, 0, stream>>>(qkv, lin_w, Xo);

    fc_gemm<<<ROWS_FC/16, 256, 0, stream>>>(Xo, Wfc, bfc, (float*)d_out);
    col_reduce<<<dim3(96, 1), 256, 0, stream>>>((float*)d_out, fsum, fsumsq, ROWS_FC, ROWS_FC/96);
    fc_stats<<<1, 64, 0, stream>>>(fsum, fsumsq, gfc, befc, fsc, fsh);
    bn_out<<<TOT/256, 256, 0, stream>>>((float*)d_out, fsc, fsh);
}

// Round 5
// 905.739 us; speedup vs baseline: 2.8705x; 1.1442x over previous
//
#include <hip/hip_runtime.h>
#include <math.h>

#define TS 12
#define HEADS 8
#define DH 8
#define DD 64
#define BB 16
#define NN 325
#define BN (BB*NN)               // 5200
#define TOT (TS*BN*DD)           // 3,993,600
#define ROWS_FC (BB*TS*NN)       // 62,400
#define NPAD 336                 // 21 tiles of 16
#define NT 21
constexpr float EPS_ = 1e-5f;
constexpr float SCALE_ = 0.35355339059327373f; // 1/sqrt(8)

typedef _Float16 f16x4 __attribute__((ext_vector_type(4)));
typedef float    f32x4 __attribute__((ext_vector_type(4)));

// ---------------- K1: QKV GEMM (16 rows/block) ----------------
__global__ __launch_bounds__(256) void qkv_gemm(
    const float* __restrict__ X, const float* __restrict__ STE,
    const float* __restrict__ Wqkv, const float* __restrict__ bqkv,
    float* __restrict__ Y)
{
    __shared__ float Wl[128*64];
    int t = blockIdx.y;
    int tid = threadIdx.x;
    for (int i = tid; i < 2048; i += 256)
        ((float4*)Wl)[i] = ((const float4*)Wqkv)[i];
    __syncthreads();
    int c = tid & 63, rl = tid >> 6;
    #pragma unroll
    for (int rr = 0; rr < 4; ++rr) {
        int r = blockIdx.x * 16 + rr * 4 + rl;
        int b = r / NN, n = r % NN;
        const float* xr = X   + (((size_t)b*TS + t)*NN + n)*DD;
        const float* sr = STE + (((size_t)b*TS + t)*NN + n)*DD;
        float acc = bqkv[c];
        #pragma unroll 8
        for (int k = 0; k < 64; ++k) acc += xr[k] * Wl[k*64 + c];
        #pragma unroll 8
        for (int k = 0; k < 64; ++k) acc += sr[k] * Wl[(64+k)*64 + c];
        Y[((size_t)t*BN + r)*64 + c] = acc;
    }
}

// ---------------- K2: column reduce (sum, sumsq) over [t][R][64] ----------------
__global__ __launch_bounds__(256) void col_reduce(
    const float* __restrict__ src, float* __restrict__ osum, float* __restrict__ osumsq,
    int R, int chunkrows)
{
    __shared__ float red[256];
    int t = blockIdx.y;
    int tid = threadIdx.x;
    int c = tid & 63, rl = tid >> 6;
    int r0 = blockIdx.x * chunkrows;
    int r1 = r0 + chunkrows;
    float s = 0.f, s2 = 0.f;
    for (int r = r0 + rl; r < r1; r += 4) {
        float v = src[((size_t)t*R + r)*64 + c];
        s += v; s2 += v*v;
    }
    red[tid] = s; __syncthreads();
    if (tid < 64) atomicAdd(&osum[t*64 + tid], red[tid] + red[tid+64] + red[tid+128] + red[tid+192]);
    __syncthreads();
    red[tid] = s2; __syncthreads();
    if (tid < 64) atomicAdd(&osumsq[t*64 + tid], red[tid] + red[tid+64] + red[tid+128] + red[tid+192]);
}

// ---------------- K3: finalize QKV BN stats ----------------
__global__ void qkv_stats(const float* __restrict__ qsum, const float* __restrict__ qsumsq,
                          const float* __restrict__ g, const float* __restrict__ be,
                          float* __restrict__ qsc, float* __restrict__ qsh)
{
    int i = blockIdx.x * blockDim.x + threadIdx.x;
    if (i >= TS*64) return;
    int c = i & 63;
    float mean = qsum[i] * (1.0f / BN);
    float var  = qsumsq[i] * (1.0f / BN) - mean*mean;
    float sc = g[c] * rsqrtf(var + EPS_);
    qsc[i] = sc;
    qsh[i] = be[c] - mean * sc;
}

// ---------------- K4: BN+ReLU + relayout to f16 [t][b][h][n][8] ----------------
__global__ __launch_bounds__(256) void bn_relayout_h(
    const float* __restrict__ Y, const float* __restrict__ qsc, const float* __restrict__ qsh,
    _Float16* __restrict__ qkvh)
{
    size_t idx = (size_t)blockIdx.x * 256 + threadIdx.x;
    if (idx >= TOT) return;
    int c = (int)(idx & 63);
    size_t tr = idx >> 6;
    int t = (int)(tr / BN);
    int r = (int)(tr % BN);
    float v = fmaxf(Y[idx] * qsc[t*64 + c] + qsh[t*64 + c], 0.0f);
    int b = r / NN, n = r % NN, h = c >> 3, d = c & 7;
    qkvh[((((size_t)t*BB + b)*HEADS + h)*NN + n)*DH + d] = (_Float16)v;
}

// ---------------- K5: init Xo with lin_b ----------------
__global__ __launch_bounds__(256) void xo_init(
    float* __restrict__ Xo, const float* __restrict__ lin_b)
{
    size_t idx = (size_t)blockIdx.x * 256 + threadIdx.x;
    if (idx >= TOT) return;
    int c = (int)(idx & 63);
    size_t row = idx >> 6;
    int s = (int)((row / NN) % TS);
    Xo[idx] = lin_b[s*64 + c];
}

// ---------------- K6: MFMA attention + per-step linear ----------------
// Block = (p=(s,j), b, h), 4 waves. S^T = K·Q^T via mfma_f32_16x16x16_f16:
// C-frag (row=m=4q+reg, col=n=l&15) == B-frag layout (k=4q+j, col=l&15) needed
// for O^T = V^T·P^T, so exp'd scores feed PV with zero cross-lane movement.
// Two-pass softmax (recompute S after max) keeps P in [0,1] for f16.
__global__ __launch_bounds__(256, 4) void attn_lin_mfma(
    const _Float16* __restrict__ qkvh, const float* __restrict__ lin_w,
    float* __restrict__ Xo)
{
    int p = blockIdx.x, b = blockIdx.y, h = blockIdx.z;
    int s = 0, base = 0;
    while (base + s + 1 <= p) { base += s + 1; ++s; }
    int j = p - base;

    __shared__ _Float16 Kl[NPAD*8];          // [m][k], rows m>=325 zero
    __shared__ _Float16 VT[16][NPAD+8];      // [d][m] pitch 344, d>=8 & m>=325 zero
    __shared__ float    wl[8*64];            // lin_w slice [d][c]
    __shared__ float    olds[4][16][8];      // per-wave o strip

    int tid  = threadIdx.x;
    int lane = tid & 63, wv = tid >> 6;
    int lq = lane >> 4, lr = lane & 15;

    // zero K/VT pads
    for (int i = tid; i < (NPAD*8)/2; i += 256) ((unsigned*)Kl)[i] = 0u;
    for (int i = tid; i < (16*(NPAD+8))/2; i += 256) ((unsigned*)(&VT[0][0]))[i] = 0u;
    __syncthreads();
    // stage K ([m][k] contiguous copy), V^T (transpose), wl
    const _Float16* kvsrc = qkvh + (((size_t)j*BB + b)*HEADS + h)*(NN*DH);
    for (int i = tid; i < (NN*DH)/2; i += 256) ((unsigned*)Kl)[i] = ((const unsigned*)kvsrc)[i];
    for (int i = tid; i < NN*DH; i += 256) { int m = i >> 3, d = i & 7; VT[d][m] = kvsrc[i]; }
    for (int i = tid; i < 512; i += 256)
        wl[i] = lin_w[((size_t)s*768 + j*64 + h*8 + (i >> 6))*64 + (i & 63)];
    __syncthreads();

    float wreg[8];
    #pragma unroll
    for (int d = 0; d < 8; ++d) wreg[d] = wl[d*64 + lane];

    const _Float16* qh = qkvh + (((size_t)s*BB + b)*HEADS + h)*(NN*DH);

    for (int st = wv; st < NT; st += 4) {
        int n0 = st * 16;
        // Q B-frag: lane holds Q[n0+lr][4*lq+i] (k>=8 -> 0), pre-scaled
        f16x4 qf = {0,0,0,0};
        int nq = n0 + lr;
        if (lq < 2 && nq < NN) qf = *(const f16x4*)(qh + nq*DH + lq*4);
        qf *= (_Float16)SCALE_;

        // pass 1: row max (padded zeros included -> max>=0, harmless)
        float mx = 0.f;
        for (int mt = 0; mt < NT; ++mt) {
            f16x4 kf = {0,0,0,0};
            if (lq < 2) kf = *(const f16x4*)(&Kl[(mt*16 + lr)*8 + lq*4]);
            f32x4 sA = __builtin_amdgcn_mfma_f32_16x16x16f16(kf, qf, (f32x4){0.f,0.f,0.f,0.f}, 0, 0, 0);
            mx = fmaxf(mx, fmaxf(fmaxf(sA[0], sA[1]), fmaxf(sA[2], sA[3])));
        }
        mx = fmaxf(mx, __shfl_xor(mx, 16));
        mx = fmaxf(mx, __shfl_xor(mx, 32));

        // pass 2: exp(S-mx), accumulate den and O^T = V^T · P^T
        f32x4 ot = {0.f, 0.f, 0.f, 0.f};
        float den = 0.f;
        for (int mt = 0; mt < NT; ++mt) {
            f16x4 kf = {0,0,0,0};
            if (lq < 2) kf = *(const f16x4*)(&Kl[(mt*16 + lr)*8 + lq*4]);
            f32x4 sA = __builtin_amdgcn_mfma_f32_16x16x16f16(kf, qf, (f32x4){0.f,0.f,0.f,0.f}, 0, 0, 0);
            f16x4 pf;
            #pragma unroll
            for (int r = 0; r < 4; ++r) {
                float e = __expf(sA[r] - mx);
                if (mt*16 + lq*4 + r >= NN) e = 0.f;   // mask pad rows
                den += e;
                pf[r] = (_Float16)e;
            }
            f16x4 vf = *(const f16x4*)(&VT[lr][mt*16 + lq*4]);
            ot = __builtin_amdgcn_mfma_f32_16x16x16f16(vf, pf, ot, 0, 0, 0);
        }
        den += __shfl_xor(den, 16);
        den += __shfl_xor(den, 32);
        float inv = 1.0f / den;

        // stage normalized o strip: lane holds O^T[d=4*lq+r][n=lr]
        if (lq < 2) {
            #pragma unroll
            for (int r = 0; r < 4; ++r) olds[wv][lr][lq*4 + r] = ot[r] * inv;
        }
        __asm__ volatile("" ::: "memory");

        // linear slice: Xo[b,s,n0+n][c] += sum_d o[n][d]*wl[d][c]
        int nmax = NN - n0; if (nmax > 16) nmax = 16;
        float* xb = Xo + (((size_t)b*TS + s)*NN + n0)*64 + lane;
        for (int n = 0; n < nmax; ++n) {
            const float* o8 = olds[wv][n];
            float4 oa = *(const float4*)o8;
            float4 ob = *(const float4*)(o8 + 4);
            float v = oa.x*wreg[0] + oa.y*wreg[1] + oa.z*wreg[2] + oa.w*wreg[3]
                    + ob.x*wreg[4] + ob.y*wreg[5] + ob.z*wreg[6] + ob.w*wreg[7];
            atomicAdd(xb + (size_t)n*64, v);
        }
    }
}

// ---------------- K7: fc GEMM (16 rows/block) ----------------
__global__ __launch_bounds__(256) void fc_gemm(
    const float* __restrict__ Xo, const float* __restrict__ Wfc, const float* __restrict__ bfc,
    float* __restrict__ Yout)
{
    __shared__ float Wl[64*64];
    int tid = threadIdx.x;
    for (int i = tid; i < 1024; i += 256)
        ((float4*)Wl)[i] = ((const float4*)Wfc)[i];
    __syncthreads();
    int c = tid & 63, rl = tid >> 6;
    #pragma unroll
    for (int rr = 0; rr < 4; ++rr) {
        size_t r = (size_t)blockIdx.x * 16 + rr * 4 + rl;
        const float* xr = Xo + r * 64;
        float acc = bfc[c];
        #pragma unroll 8
        for (int k = 0; k < 64; ++k) acc += xr[k] * Wl[k*64 + c];
        Yout[r*64 + c] = acc;
    }
}

// ---------------- K8: finalize fc BN stats ----------------
__global__ void fc_stats(const float* __restrict__ fsum, const float* __restrict__ fsumsq,
                         const float* __restrict__ g, const float* __restrict__ be,
                         float* __restrict__ fsc, float* __restrict__ fsh)
{
    int c = threadIdx.x;
    if (c >= 64) return;
    float mean = fsum[c] * (1.0f / ROWS_FC);
    float var  = fsumsq[c] * (1.0f / ROWS_FC) - mean*mean;
    float sc = g[c] * rsqrtf(var + EPS_);
    fsc[c] = sc;
    fsh[c] = be[c] - mean * sc;
}

// ---------------- K9: final BN+ReLU in place on d_out ----------------
__global__ __launch_bounds__(256) void bn_out(
    float* __restrict__ out, const float* __restrict__ fsc, const float* __restrict__ fsh)
{
    size_t idx = (size_t)blockIdx.x * 256 + threadIdx.x;
    if (idx >= TOT) return;
    int c = (int)(idx & 63);
    out[idx] = fmaxf(out[idx] * fsc[c] + fsh[c], 0.0f);
}

extern "C" void kernel_launch(void* const* d_in, const int* in_sizes, int n_in,
                              void* d_out, int out_size, void* d_ws, size_t ws_size,
                              hipStream_t stream)
{
    const float* X     = (const float*)d_in[0];
    const float* STE   = (const float*)d_in[1];
    const float* Wqkv  = (const float*)d_in[2];
    const float* bqkv  = (const float*)d_in[3];
    const float* gqkv  = (const float*)d_in[4];
    const float* beqkv = (const float*)d_in[5];
    const float* lin_w = (const float*)d_in[6];
    const float* lin_b = (const float*)d_in[7];
    const float* Wfc   = (const float*)d_in[8];
    const float* bfc   = (const float*)d_in[9];
    const float* gfc   = (const float*)d_in[10];
    const float* befc  = (const float*)d_in[11];

    float* ws    = (float*)d_ws;
    float* Y     = ws;                               // TOT f32
    _Float16* qkvh = (_Float16*)(ws + (size_t)TOT);  // TOT f16 = TOT/2 f32 slots
    float* Xo    = ws + (size_t)TOT + TOT/2;         // TOT f32
    float* st    = ws + (size_t)2*TOT + TOT/2;
    float* qsum   = st;            // 768
    float* qsumsq = st + 768;      // 768
    float* fsum   = st + 1536;     // 64
    float* fsumsq = st + 1600;     // 64  -> first 1664 floats zeroed each call
    float* qsc    = st + 1664;     // 768
    float* qsh    = st + 2432;     // 768
    float* fsc    = st + 3200;     // 64
    float* fsh    = st + 3264;     // 64

    hipMemsetAsync(st, 0, 1664 * sizeof(float), stream);

    qkv_gemm<<<dim3(BN/16, TS), 256, 0, stream>>>(X, STE, Wqkv, bqkv, Y);
    col_reduce<<<dim3(8, TS), 256, 0, stream>>>(Y, qsum, qsumsq, BN, BN/8);
    qkv_stats<<<3, 256, 0, stream>>>(qsum, qsumsq, gqkv, beqkv, qsc, qsh);
    bn_relayout_h<<<TOT/256, 256, 0, stream>>>(Y, qsc, qsh, qkvh);
    xo_init<<<TOT/256, 256, 0, stream>>>(Xo, lin_b);

    attn_lin_mfma<<<dim3(78, BB, HEADS), 256, 0, stream>>>(qkvh, lin_w, Xo);

    fc_gemm<<<ROWS_FC/16, 256, 0, stream>>>(Xo, Wfc, bfc, (float*)d_out);
    col_reduce<<<dim3(96, 1), 256, 0, stream>>>((float*)d_out, fsum, fsumsq, ROWS_FC, ROWS_FC/96);
    fc_stats<<<1, 64, 0, stream>>>(fsum, fsumsq, gfc, befc, fsc, fsh);
    bn_out<<<TOT/256, 256, 0, stream>>>((float*)d_out, fsc, fsh);
}